// Round 11
// baseline (124.030 us; speedup 1.0000x reference)
//
#include <hip/hip_runtime.h>
#include <math.h>

// Elementwise OxideModel 'second' branch.
// Ladder: R3 faithful 49.2us (VALU-bound) -> R5 algebra restructure ~35us
// -> R9 nt+unroll ~40us (nt bypassed L3-resident input: regression)
// -> R10 2M threads x 2 chains ~33us (neutral-ish: per-thread libm preamble
//    grew to ~25 ops/elem, confounding the added parallelism).
// R11: fast-math preamble (exp2/log2/rcp based, ~5x cheaper) + 4 independent
// f32x4 chains/thread at 1M threads (4 loads in flight, 16 elem/thread).

typedef float f32x4 __attribute__((ext_vector_type(4)));

__device__ __forceinline__ float fast_rcp(float v) { return __builtin_amdgcn_rcpf(v); }
__device__ __forceinline__ float fast_exp(float v) {
    return __builtin_amdgcn_exp2f(v * 1.44269504088896f);
}
__device__ __forceinline__ float fast_log(float v) {
    return __builtin_amdgcn_logf(v) * 0.6931471805599453f;
}
__device__ __forceinline__ float fast_tanh(float v) {
    // tanh(v) = (e^{2v}-1)/(e^{2v}+1); exact 0 at v=0 (bench case)
    float t = __builtin_amdgcn_exp2f(v * 2.885390081777927f);
    return (t - 1.0f) * fast_rcp(t + 1.0f);
}

struct Scalars {
    // fallback (x<=1 series) path support — mirrors reference
    float E, U, K, expK, coef, fsT, IsT;
    // restructured main-path constants
    float A;   // exp(xT)          : exp(f(st)-f(sT)) = A * e
    float B;   // coef * expK      : coef*Ist = B * st*e*R(x)
    float C;   // U + coef * IsT   : inner = C - B*st*e*R(x)
};

// Q - P of A&S 5.1.56 (x^4 cancels; folded in coefficient space)
__device__ __forceinline__ float poly_N(float x) {
    return fmaf(fmaf(fmaf(0.9999936053f, x, 7.5739391756f), x, 12.4648921902f),
                x, 3.6907231885f);
}
__device__ __forceinline__ float poly_Q(float x) {
    return fmaf(fmaf(fmaf((x + 9.5733223454f), x, 25.6329561486f), x,
                     21.0996530827f), x, 3.9584969228f);
}

__device__ __forceinline__ Scalars make_scalars(float gshift, float E_param,
                                                float T_max_delta, float V_max) {
    Scalars s;
    s.E = fminf(fmaxf(fast_exp(E_param) * 1000.0f, 1e-10f), 1e10f);
    float V = fminf(fmaxf(fast_exp(V_max), 1e-10f), 1e10f);
    float T_max = 500.0f + 50.0f * fast_tanh(T_max_delta) + gshift;
    float sT = fmaxf(T_max, 1e-10f);
    s.U = __builtin_amdgcn_sqrtf(V);
    float rsT = fast_rcp(sT);
    float xT = s.E * rsT;
    s.K = xT + (2.0f / 3.0f) * fast_log(1.5f * s.E * s.U * (rsT * rsT));
    s.expK = fast_exp(s.K);
    s.fsT = s.K - xT;
    s.coef = (1.0f / 3.0f) * fast_exp(s.fsT * 0.5f);
    float eT = fast_exp(-xT);
    if (xT > 1.0f) {
        // restructured integral(sT): expK * sT * eT * (Q-P)/Q
        s.IsT = s.expK * sT * eT * (poly_N(xT) * fast_rcp(poly_Q(xT)));
    } else {
        // reference series branch (dead for bench params: xT = 10)
        float xs = fminf(fmaxf(xT, 1e-30f), 1.0f);
        float term = 1.0f, acc = 0.0f;
#pragma unroll 1
        for (int k = 1; k <= 25; ++k) {
            term = term * (-xs) / (float)k;
            acc += term / (float)k;
        }
        float ei = 0.5772156649015329f + fast_log(xs) + acc;
        s.IsT = s.expK * (sT * eT + s.E * ei);
    }
    s.A = fast_exp(xT);
    s.B = s.coef * s.expK;
    s.C = s.U + s.coef * s.IsT;
    return s;
}

__device__ __forceinline__ float compute_one(float t, const Scalars& s) {
    float st = fmaxf(t, 1e-10f);
    float x = s.E * __builtin_amdgcn_rcpf(st);
    float e = __builtin_amdgcn_exp2f(x * -1.44269504088896f);  // exp(-x)
    if (x <= 1.0f) {
        // reference small-x path (uniformly dead for t in [300,800]: x>=6.25;
        // s_cbranch_execz skips it)
        float xs = fminf(fmaxf(x, 1e-30f), 1.0f);
        float term = 1.0f, acc = 0.0f;
#pragma unroll 1
        for (int k = 1; k <= 25; ++k) {
            term = term * (-xs) / (float)k;
            acc += term / (float)k;
        }
        float ei = 0.5772156649015329f + fast_log(xs) + acc;
        float Ist = s.expK * (st * e + s.E * ei);
        float exp_arg = fminf(fmaxf((s.K - x) - s.fsT, -100.0f), 100.0f);
        float inner = s.U - s.coef * (Ist - s.IsT);
        float r = fmaxf(inner, 0.0f);
        return fast_exp(exp_arg) * r * r;
    }
    // main path: out = exp(xT-x) * relu(U - coef*(Ist - IsT))^2
    //          = (A*e) * relu(C - B*st*e*(Q-P)/Q)^2
    float R = poly_N(x) * __builtin_amdgcn_rcpf(poly_Q(x));
    float inner = fmaf(-s.B * (st * e), R, s.C);
    float r = fmaxf(inner, 0.0f);
    return (s.A * e) * (r * r);
}

__device__ __forceinline__ f32x4 compute_four(f32x4 v, const Scalars& s) {
    f32x4 o;
    o.x = compute_one(v.x, s);
    o.y = compute_one(v.y, s);
    o.z = compute_one(v.z, s);
    o.w = compute_one(v.w, s);
    return o;
}

extern "C" __global__ void __launch_bounds__(256, 8)
oxide_kernel(const float* __restrict__ in,
             const float* __restrict__ p_gs,
             const float* __restrict__ p_E,
             const float* __restrict__ p_Td,
             const float* __restrict__ p_V,
             float* __restrict__ out, int n) {
    Scalars s = make_scalars(p_gs[0], p_E[0], p_Td[0], p_V[0]);

    int tid = blockIdx.x * blockDim.x + threadIdx.x;
    int nthreads = gridDim.x * blockDim.x;   // 1M
    int n4 = n >> 2;                         // 4M quads
    const f32x4* __restrict__ in4 = (const f32x4*)in;
    f32x4* __restrict__ out4 = (f32x4*)out;

    // 4 independent chains; loads issued back-to-back (4 VMEM in flight).
    int i0 = tid;
    int i1 = tid + nthreads;
    int i2 = tid + 2 * nthreads;
    int i3 = tid + 3 * nthreads;
    bool b0 = i0 < n4, b1 = i1 < n4, b2 = i2 < n4, b3 = i3 < n4;
    f32x4 v0, v1, v2, v3;
    if (b0) v0 = in4[i0];
    if (b1) v1 = in4[i1];
    if (b2) v2 = in4[i2];
    if (b3) v3 = in4[i3];
    if (b0) out4[i0] = compute_four(v0, s);
    if (b1) out4[i1] = compute_four(v1, s);
    if (b2) out4[i2] = compute_four(v2, s);
    if (b3) out4[i3] = compute_four(v3, s);

    // tail (n not divisible by 4) — dead for N=2^24, kept for generality
    int base = n4 << 2;
    for (int k = base + tid; k < n; k += nthreads) {
        out[k] = compute_one(in[k], s);
    }
}

extern "C" void kernel_launch(void* const* d_in, const int* in_sizes, int n_in,
                              void* d_out, int out_size, void* d_ws, size_t ws_size,
                              hipStream_t stream) {
    const float* in = (const float*)d_in[0];
    const float* gs = (const float*)d_in[1];
    const float* Ep = (const float*)d_in[2];
    const float* Td = (const float*)d_in[3];
    const float* Vm = (const float*)d_in[4];
    float* out = (float*)d_out;
    int n = in_sizes[0];

    const int threads = 256;
    // 4 quads/thread: 4096 blocks at N=2^24 -> 1M threads, 16 elem/thread,
    // preamble ~2.5 ops/elem, 4 loads in flight per thread.
    int n4 = n >> 2;
    int blocks = (n4 + threads * 4 - 1) / (threads * 4);
    oxide_kernel<<<blocks, threads, 0, stream>>>(in, gs, Ep, Td, Vm, out, n);
}